// Round 2
// baseline (494.859 us; speedup 1.0000x reference)
//
#include <hip/hip_runtime.h>
#include <cstdint>

static constexpr int NN = 16384, FF = 256, GG = 64, EE = 131072, LL = 3;
static constexpr int HIDN = 512, IU = 32640, IN1 = 33408;
#define EPSV 1e-5f

// ---------------- degree / count histograms ----------------
__global__ __launch_bounds__(256) void k_deg(const int* __restrict__ dst, int* __restrict__ deg) {
  int e = blockIdx.x * 256 + threadIdx.x;
  if (e < EE) atomicAdd(&deg[dst[e]], 1);
}
__global__ __launch_bounds__(256) void k_cnt(const int* __restrict__ batch, int* __restrict__ cnt) {
  int n = blockIdx.x * 256 + threadIdx.x;
  if (n < NN) atomicAdd(&cnt[batch[n]], 1);
}

// ---------------- layer GEMM: C = deg * (A @ W + b), M=16384 K=N=256 ----------------
__global__ __launch_bounds__(256) void k_gemm_layer(const float* __restrict__ A,
                                                    const float* __restrict__ W,
                                                    const float* __restrict__ bias,
                                                    const int* __restrict__ deg,
                                                    float* __restrict__ C) {
  __shared__ float As[16][68];  // transposed: As[k][m]
  __shared__ float Bs[16][68];  // Bs[k][n]
  int m0 = blockIdx.y * 64, n0 = blockIdx.x * 64;
  int tid = threadIdx.x;
  int tx = tid & 15, ty = tid >> 4;
  int ar = tid >> 2, akq = (tid & 3) << 2;
  int bk = tid >> 4, bc = (tid & 15) << 2;
  float acc[4][4] = {};
  for (int k0 = 0; k0 < FF; k0 += 16) {
    float4 av = *(const float4*)(A + (size_t)(m0 + ar) * FF + k0 + akq);
    As[akq + 0][ar] = av.x;
    As[akq + 1][ar] = av.y;
    As[akq + 2][ar] = av.z;
    As[akq + 3][ar] = av.w;
    *(float4*)(&Bs[bk][bc]) = *(const float4*)(W + (size_t)(k0 + bk) * FF + n0 + bc);
    __syncthreads();
#pragma unroll
    for (int k = 0; k < 16; ++k) {
      const float* ap = &As[k][ty * 4];
      const float* bp = &Bs[k][tx * 4];
      float a[4], b[4];
#pragma unroll
      for (int i = 0; i < 4; ++i) { a[i] = ap[i]; b[i] = bp[i]; }
#pragma unroll
      for (int i = 0; i < 4; ++i)
#pragma unroll
        for (int j = 0; j < 4; ++j) acc[i][j] += a[i] * b[j];
    }
    __syncthreads();
  }
  float bb[4];
#pragma unroll
  for (int j = 0; j < 4; ++j) bb[j] = bias[n0 + tx * 4 + j];
#pragma unroll
  for (int i = 0; i < 4; ++i) {
    int row = m0 + ty * 4 + i;
    float df = (float)(deg[row] + 1);  // +1 = self loop
    float4 o;
    o.x = df * (acc[i][0] + bb[0]);
    o.y = df * (acc[i][1] + bb[1]);
    o.z = df * (acc[i][2] + bb[2]);
    o.w = df * (acc[i][3] + bb[3]);
    *(float4*)(C + (size_t)row * FF + n0 + tx * 4) = o;
  }
}

// ---------------- pooling: pooled[g][lofs+f] += sum over rows of graph g ----------------
__global__ __launch_bounds__(256) void k_pool(const float* __restrict__ h,
                                              const int* __restrict__ batch,
                                              float* __restrict__ pooled, int lofs) {
  int n0 = blockIdx.x * 64;
  int f = threadIdx.x;
  float run = 0.f;
  int gprev = batch[n0];
  for (int r = 0; r < 64; ++r) {
    int n = n0 + r;
    int g = batch[n];
    if (g != gprev) {
      atomicAdd(&pooled[(size_t)gprev * (FF * LL) + lofs + f], run);
      run = 0.f;
      gprev = g;
    }
    run += h[(size_t)n * FF + f];
  }
  atomicAdd(&pooled[(size_t)gprev * (FF * LL) + lofs + f], run);
}

// ---------------- xt extraction + BN over G, writes z[:, 0:IU) ----------------
__global__ __launch_bounds__(256) void k_xt_bn(const float* __restrict__ x,
                                               const float* __restrict__ gamma,
                                               const float* __restrict__ beta,
                                               float* __restrict__ z) {
  int i = blockIdx.x;
  int j = threadIdx.x;
  if (j <= i) return;
  int p = i * 255 - (i * (i - 1)) / 2 + (j - i - 1);
  float vals[64];
  float s = 0.f, s2 = 0.f;
#pragma unroll
  for (int g = 0; g < 64; ++g) {
    float v = x[(size_t)(g * 256 + i) * FF + j];
    vals[g] = v;
    s += v;
    s2 += v * v;
  }
  float m = s * (1.f / 64.f);
  float var = s2 * (1.f / 64.f) - m * m;
  float rs = rsqrtf(var + EPSV) * gamma[p];
  float bb = beta[p];
#pragma unroll
  for (int g = 0; g < 64; ++g) z[(size_t)g * IN1 + p] = (vals[g] - m) * rs + bb;
}

// ---------------- pooled mean + BN over G, writes z[:, IU:IN1) ----------------
__global__ __launch_bounds__(256) void k_pool_bn(const float* __restrict__ pooled,
                                                 const int* __restrict__ cnt,
                                                 const float* __restrict__ gamma,
                                                 const float* __restrict__ beta,
                                                 float* __restrict__ z) {
  int q = blockIdx.x * 256 + threadIdx.x;
  if (q >= FF * LL) return;
  float vals[64];
  float s = 0.f, s2 = 0.f;
#pragma unroll
  for (int g = 0; g < 64; ++g) {
    float v = pooled[(size_t)g * (FF * LL) + q] / (float)cnt[g];
    vals[g] = v;
    s += v;
    s2 += v * v;
  }
  float m = s * (1.f / 64.f);
  float var = s2 * (1.f / 64.f) - m * m;
  float rs = rsqrtf(var + EPSV) * gamma[q];
  float bb = beta[q];
#pragma unroll
  for (int g = 0; g < 64; ++g) z[(size_t)g * IN1 + IU + q] = (vals[g] - m) * rs + bb;
}

// ---------------- skinny GEMM (M=64) with K-split: partial[s][g][h] ----------------
template <int H2>
__global__ __launch_bounds__(256) void k_skinny(const float* __restrict__ Z,
                                                const float* __restrict__ W,
                                                float* __restrict__ partial, int K, int N) {
  __shared__ float zl[64][128];
  int h0 = blockIdx.x * 64 * H2;
  int s = blockIdx.y, S = gridDim.y;
  int hl = threadIdx.x & 63, gq = threadIdx.x >> 6;
  float acc[16][H2];
#pragma unroll
  for (int i = 0; i < 16; ++i)
#pragma unroll
    for (int u = 0; u < H2; ++u) acc[i][u] = 0.f;
  int nchunks = (K + 127) >> 7;
  for (int c = s; c < nchunks; c += S) {
    int p0 = c << 7;
    int plen = min(128, K - p0);
    for (int idx = threadIdx.x; idx < 64 * 128; idx += 256) {
      int g = idx >> 7, pp = idx & 127;
      zl[g][pp] = (pp < plen) ? Z[(size_t)g * K + p0 + pp] : 0.f;
    }
    __syncthreads();
    for (int pp = 0; pp < plen; ++pp) {
      float w[H2];
#pragma unroll
      for (int u = 0; u < H2; ++u) w[u] = W[(size_t)(p0 + pp) * N + h0 + u * 64 + hl];
#pragma unroll
      for (int i = 0; i < 16; ++i) {
        float zv = zl[gq * 16 + i][pp];
#pragma unroll
        for (int u = 0; u < H2; ++u) acc[i][u] += zv * w[u];
      }
    }
    __syncthreads();
  }
#pragma unroll
  for (int i = 0; i < 16; ++i)
#pragma unroll
    for (int u = 0; u < H2; ++u)
      partial[((size_t)s * 64 + gq * 16 + i) * N + h0 + u * 64 + hl] = acc[i][u];
}

// ---------------- reduce K-splits + bias ----------------
__global__ __launch_bounds__(256) void k_reduce(const float* __restrict__ partial,
                                                const float* __restrict__ bias,
                                                float* __restrict__ out, int S, int N) {
  int idx = blockIdx.x * 256 + threadIdx.x;
  if (idx >= 64 * N) return;
  int h = idx % N;
  float a = bias[h];
  for (int s = 0; s < S; ++s) a += partial[(size_t)s * 64 * N + idx];
  out[idx] = a;
}

// ---------------- column-wise BN over 64 rows + ReLU ----------------
__global__ __launch_bounds__(64) void k_bn_relu(const float* __restrict__ in,
                                                const float* __restrict__ gamma,
                                                const float* __restrict__ beta,
                                                float* __restrict__ out, int N) {
  int h = blockIdx.x;
  int g = threadIdx.x;
  float v = in[(size_t)g * N + h];
  float s = v, s2 = v * v;
#pragma unroll
  for (int o = 32; o > 0; o >>= 1) {
    s += __shfl_xor(s, o);
    s2 += __shfl_xor(s2, o);
  }
  float m = s * (1.f / 64.f);
  float var = s2 * (1.f / 64.f) - m * m;
  float r = (v - m) * rsqrtf(var + EPSV) * gamma[h] + beta[h];
  out[(size_t)g * N + h] = fmaxf(r, 0.f);
}

// ---------------- final: out = A @ w4 + b4, [64,256]@[256,2] ----------------
__global__ __launch_bounds__(128) void k_final(const float* __restrict__ A,
                                               const float* __restrict__ w4,
                                               const float* __restrict__ b4,
                                               float* __restrict__ out) {
  int t = threadIdx.x;
  if (t >= 128) return;
  int g = t >> 1, c = t & 1;
  float a = b4[c];
  for (int k = 0; k < 256; ++k) a += A[(size_t)g * 256 + k] * w4[k * 2 + c];
  out[g * 2 + c] = a;
}

extern "C" void kernel_launch(void* const* d_in, const int* in_sizes, int n_in,
                              void* d_out, int out_size, void* d_ws, size_t ws_size,
                              hipStream_t stream) {
  const float* x = (const float*)d_in[0];
  const int* edge = (const int*)d_in[1];
  const int* batch = (const int*)d_in[2];
  // d_in[3],[4] lin_src_w/b: dead. d_in[7],[8] att_w/b: dead (softmax over singleton = 1).
  const float* lin_dst_w = (const float*)d_in[5];
  const float* lin_dst_b = (const float*)d_in[6];
  const float* bn_g = (const float*)d_in[9];
  const float* bn_b = (const float*)d_in[10];
  const float* bnh_g = (const float*)d_in[11];
  const float* bnh_b = (const float*)d_in[12];
  const float* w1 = (const float*)d_in[13];
  const float* b1 = (const float*)d_in[14];
  const float* g1 = (const float*)d_in[15];
  const float* be1 = (const float*)d_in[16];
  const float* w2 = (const float*)d_in[17];
  const float* b2 = (const float*)d_in[18];
  const float* g2 = (const float*)d_in[19];
  const float* be2 = (const float*)d_in[20];
  const float* w3 = (const float*)d_in[21];
  const float* b3 = (const float*)d_in[22];
  const float* g3 = (const float*)d_in[23];
  const float* be3 = (const float*)d_in[24];
  const float* w4 = (const float*)d_in[25];
  const float* b4 = (const float*)d_in[26];
  const int* dstp = edge + EE;  // edge_index[1]

  char* ws = (char*)d_ws;
  int* deg = (int*)(ws);                                     // 64 KB
  int* cnt = (int*)(ws + 65536);                             // 256 B
  float* bufA = (float*)(ws + 131072);                       // 16 MiB
  float* bufB = (float*)(ws + 131072 + 16777216);            // 16 MiB
  float* pooled = (float*)(ws + 131072 + 2 * 16777216);      // 192 KB
  char* tail = ws + 131072 + 2 * 16777216 + 196608;
  float* m1 = (float*)(tail);                                // 64x512
  float* m1b = (float*)(tail + 131072);
  float* m2 = (float*)(tail + 262144);                       // 64x256
  float* m2b = (float*)(tail + 262144 + 65536);
  float* m3 = (float*)(tail + 262144 + 131072);
  float* m3b = (float*)(tail + 262144 + 196608);
  float* z = bufA;       // reused after layer-3 pooling (8.55 MB <= 16 MiB)
  float* partial = bufB; // S=128: 128*64*512*4 = 16,777,216 B == bufB exactly

  hipMemsetAsync(ws, 0, 131072, stream);            // deg + cnt
  hipMemsetAsync(pooled, 0, 196608, stream);        // pooled accumulators

  k_deg<<<(EE + 255) / 256, 256, 0, stream>>>(dstp, deg);
  k_cnt<<<(NN + 255) / 256, 256, 0, stream>>>(batch, cnt);

  // ---- 3 conv layers: h = deg * (h @ Wd + bd); pooled[l] += per-graph sums ----
  const float* hin = x;
  float* houts[3] = {bufA, bufB, bufA};
  for (int l = 0; l < LL; ++l) {
    k_gemm_layer<<<dim3(4, 256), 256, 0, stream>>>(hin, lin_dst_w + (size_t)l * FF * FF,
                                                   lin_dst_b + (size_t)l * FF, deg, houts[l]);
    k_pool<<<256, 256, 0, stream>>>(houts[l], batch, pooled, l * FF);
    hin = houts[l];
  }

  // ---- build z = [BN(xt) | BN(pooled/cnt)] ----
  k_xt_bn<<<256, 256, 0, stream>>>(x, bn_g, bn_b, z);
  k_pool_bn<<<3, 256, 0, stream>>>(pooled, cnt, bnh_g, bnh_b, z);

  // ---- MLP ----
  // S=128 K-splits: partial fits bufB EXACTLY (131 splits overflowed into m1 -> race; round-1 bug)
  k_skinny<4><<<dim3(2, 128), 256, 0, stream>>>(z, w1, partial, IN1, HIDN);
  k_reduce<<<128, 256, 0, stream>>>(partial, b1, m1, 128, HIDN);
  k_bn_relu<<<HIDN, 64, 0, stream>>>(m1, g1, be1, m1b, HIDN);

  k_skinny<1><<<dim3(4, 4), 256, 0, stream>>>(m1b, w2, partial, HIDN, 256);
  k_reduce<<<64, 256, 0, stream>>>(partial, b2, m2, 4, 256);
  k_bn_relu<<<256, 64, 0, stream>>>(m2, g2, be2, m2b, 256);

  k_skinny<1><<<dim3(4, 2), 256, 0, stream>>>(m2b, w3, partial, 256, 256);
  k_reduce<<<64, 256, 0, stream>>>(partial, b3, m3, 2, 256);
  k_bn_relu<<<256, 64, 0, stream>>>(m3, g3, be3, m3b, 256);

  k_final<<<1, 128, 0, stream>>>(m3b, w4, b4, (float*)d_out);
}

// Round 3
// 439.489 us; speedup vs baseline: 1.1260x; 1.1260x over previous
//
#include <hip/hip_runtime.h>
#include <cstdint>

static constexpr int NN = 16384, FF = 256, GG = 64, EE = 131072, LL = 3;
static constexpr int HIDN = 512, IU = 32640, IN1 = 33408;
#define EPSV 1e-5f

// ---------------- degree / count histograms ----------------
__global__ __launch_bounds__(256) void k_deg(const int* __restrict__ dst, int* __restrict__ deg) {
  int e = blockIdx.x * 256 + threadIdx.x;
  if (e < EE) atomicAdd(&deg[dst[e]], 1);
}
__global__ __launch_bounds__(256) void k_cnt(const int* __restrict__ batch, int* __restrict__ cnt) {
  int n = blockIdx.x * 256 + threadIdx.x;
  if (n < NN) atomicAdd(&cnt[batch[n]], 1);
}

// ---------------- layer GEMM v2: C = deg * (A @ W + b), 128x64 tile, 8x4/thread ----------------
__global__ __launch_bounds__(256) void k_gemm_layer(const float* __restrict__ A,
                                                    const float* __restrict__ W,
                                                    const float* __restrict__ bias,
                                                    const int* __restrict__ deg,
                                                    float* __restrict__ C) {
  __shared__ float As[16][136];  // A^T tile: As[k][m], m<128
  __shared__ float Bs[16][68];   // Bs[k][n], n<64
  int m0 = blockIdx.y * 128, n0 = blockIdx.x * 64;
  int tid = threadIdx.x;
  int tx = tid & 15, ty = tid >> 4;   // cols tx*4, rows ty*8..+8
  float acc[8][4] = {};
  for (int k0 = 0; k0 < FF; k0 += 16) {
#pragma unroll
    for (int q = 0; q < 2; ++q) {
      int idx = q * 256 + tid;
      int m = idx >> 2, kq = idx & 3;
      float4 v = *(const float4*)(A + (size_t)(m0 + m) * FF + k0 + kq * 4);
      As[kq * 4 + 0][m] = v.x;
      As[kq * 4 + 1][m] = v.y;
      As[kq * 4 + 2][m] = v.z;
      As[kq * 4 + 3][m] = v.w;
    }
    {
      int k = tid >> 4, nq = tid & 15;
      *(float4*)&Bs[k][nq * 4] = *(const float4*)(W + (size_t)(k0 + k) * FF + n0 + nq * 4);
    }
    __syncthreads();
#pragma unroll
    for (int k = 0; k < 16; ++k) {
      float a[8], b[4];
      *(float4*)&a[0] = *(float4*)&As[k][ty * 8];
      *(float4*)&a[4] = *(float4*)&As[k][ty * 8 + 4];
      *(float4*)&b[0] = *(float4*)&Bs[k][tx * 4];
#pragma unroll
      for (int i = 0; i < 8; ++i)
#pragma unroll
        for (int j = 0; j < 4; ++j) acc[i][j] = fmaf(a[i], b[j], acc[i][j]);
    }
    __syncthreads();
  }
  float bb[4];
#pragma unroll
  for (int j = 0; j < 4; ++j) bb[j] = bias[n0 + tx * 4 + j];
#pragma unroll
  for (int i = 0; i < 8; ++i) {
    int row = m0 + ty * 8 + i;
    float df = (float)(deg[row] + 1);  // +1 = self loop
    float4 o;
    o.x = df * (acc[i][0] + bb[0]);
    o.y = df * (acc[i][1] + bb[1]);
    o.z = df * (acc[i][2] + bb[2]);
    o.w = df * (acc[i][3] + bb[3]);
    *(float4*)(C + (size_t)row * FF + n0 + tx * 4) = o;
  }
}

// ---------------- pooling: pooled[g][lofs+f] += sum over rows of graph g ----------------
__global__ __launch_bounds__(256) void k_pool(const float* __restrict__ h,
                                              const int* __restrict__ batch,
                                              float* __restrict__ pooled, int lofs) {
  int n0 = blockIdx.x * 64;
  int f = threadIdx.x;
  float run = 0.f;
  int gprev = batch[n0];
  for (int r = 0; r < 64; ++r) {
    int n = n0 + r;
    int g = batch[n];
    if (g != gprev) {
      atomicAdd(&pooled[(size_t)gprev * (FF * LL) + lofs + f], run);
      run = 0.f;
      gprev = g;
    }
    run += h[(size_t)n * FF + f];
  }
  atomicAdd(&pooled[(size_t)gprev * (FF * LL) + lofs + f], run);
}

// ---------------- xt extraction + BN over G, writes z[:, 0:IU) ----------------
__global__ __launch_bounds__(256) void k_xt_bn(const float* __restrict__ x,
                                               const float* __restrict__ gamma,
                                               const float* __restrict__ beta,
                                               float* __restrict__ z) {
  int i = blockIdx.x;
  int j = threadIdx.x;
  if (j <= i) return;
  int p = i * 255 - (i * (i - 1)) / 2 + (j - i - 1);
  float vals[64];
  float s = 0.f, s2 = 0.f;
#pragma unroll
  for (int g = 0; g < 64; ++g) {
    float v = x[(size_t)(g * 256 + i) * FF + j];
    vals[g] = v;
    s += v;
    s2 += v * v;
  }
  float m = s * (1.f / 64.f);
  float var = s2 * (1.f / 64.f) - m * m;
  float rs = rsqrtf(var + EPSV) * gamma[p];
  float bb = beta[p];
#pragma unroll
  for (int g = 0; g < 64; ++g) z[(size_t)g * IN1 + p] = (vals[g] - m) * rs + bb;
}

// ---------------- pooled mean + BN over G, writes z[:, IU:IN1) ----------------
__global__ __launch_bounds__(256) void k_pool_bn(const float* __restrict__ pooled,
                                                 const int* __restrict__ cnt,
                                                 const float* __restrict__ gamma,
                                                 const float* __restrict__ beta,
                                                 float* __restrict__ z) {
  int q = blockIdx.x * 256 + threadIdx.x;
  if (q >= FF * LL) return;
  float vals[64];
  float s = 0.f, s2 = 0.f;
#pragma unroll
  for (int g = 0; g < 64; ++g) {
    float v = pooled[(size_t)g * (FF * LL) + q] / (float)cnt[g];
    vals[g] = v;
    s += v;
    s2 += v * v;
  }
  float m = s * (1.f / 64.f);
  float var = s2 * (1.f / 64.f) - m * m;
  float rs = rsqrtf(var + EPSV) * gamma[q];
  float bb = beta[q];
#pragma unroll
  for (int g = 0; g < 64; ++g) z[(size_t)g * IN1 + IU + q] = (vals[g] - m) * rs + bb;
}

// ---------------- w1 GEMM: partial[s][g][h] for [64,33408]@[33408,512] ----------------
// grid (8 col-blocks of 64, 128 K-splits); 256 thr: hq=t&15 (cols n0+hq*4), gq=t>>4 (g=gq*4..+4)
// W read once, float4-coalesced, 2-deep prefetch; z chunk in LDS (broadcast scalar reads).
__global__ __launch_bounds__(256) void k_w1(const float* __restrict__ Z,
                                            const float* __restrict__ W,
                                            float* __restrict__ partial) {
  __shared__ float zl[64][132];
  int n0 = blockIdx.x * 64;
  int s = blockIdx.y;
  int tid = threadIdx.x;
  int hq = tid & 15, gq = tid >> 4;
  float acc[4][4] = {};
  for (int c = s; c < 261; c += 128) {  // 33408 = 261*128 exactly
    int p0 = c << 7;
#pragma unroll
    for (int it = 0; it < 8; ++it) {
      int idx = it * 256 + tid;
      int g = idx >> 5, kq = idx & 31;
      *(float4*)&zl[g][kq * 4] = *(const float4*)(Z + (size_t)g * IN1 + p0 + kq * 4);
    }
    __syncthreads();
    const float* wp = W + (size_t)p0 * HIDN + n0 + hq * 4;
    float4 w0 = *(const float4*)(wp);
    float4 w1 = *(const float4*)(wp + HIDN);
#pragma unroll 4
    for (int kk = 0; kk < 128; ++kk) {
      int kn = kk + 2 < 128 ? kk + 2 : 127;
      float4 w2 = *(const float4*)(wp + (size_t)kn * HIDN);
      float zv[4];
#pragma unroll
      for (int i = 0; i < 4; ++i) zv[i] = zl[gq * 4 + i][kk];
#pragma unroll
      for (int i = 0; i < 4; ++i) {
        acc[i][0] = fmaf(zv[i], w0.x, acc[i][0]);
        acc[i][1] = fmaf(zv[i], w0.y, acc[i][1]);
        acc[i][2] = fmaf(zv[i], w0.z, acc[i][2]);
        acc[i][3] = fmaf(zv[i], w0.w, acc[i][3]);
      }
      w0 = w1;
      w1 = w2;
    }
    __syncthreads();
  }
#pragma unroll
  for (int i = 0; i < 4; ++i) {
    int g = gq * 4 + i;
    *(float4*)(partial + ((size_t)s * 64 + g) * HIDN + n0 + hq * 4) = *(float4*)&acc[i][0];
  }
}

// ---------------- skinny GEMM (M=64) with K-split (kept for small w2/w3) ----------------
template <int H2>
__global__ __launch_bounds__(256) void k_skinny(const float* __restrict__ Z,
                                                const float* __restrict__ W,
                                                float* __restrict__ partial, int K, int N) {
  __shared__ float zl[64][128];
  int h0 = blockIdx.x * 64 * H2;
  int s = blockIdx.y, S = gridDim.y;
  int hl = threadIdx.x & 63, gq = threadIdx.x >> 6;
  float acc[16][H2];
#pragma unroll
  for (int i = 0; i < 16; ++i)
#pragma unroll
    for (int u = 0; u < H2; ++u) acc[i][u] = 0.f;
  int nchunks = (K + 127) >> 7;
  for (int c = s; c < nchunks; c += S) {
    int p0 = c << 7;
    int plen = min(128, K - p0);
    for (int idx = threadIdx.x; idx < 64 * 128; idx += 256) {
      int g = idx >> 7, pp = idx & 127;
      zl[g][pp] = (pp < plen) ? Z[(size_t)g * K + p0 + pp] : 0.f;
    }
    __syncthreads();
    for (int pp = 0; pp < plen; ++pp) {
      float w[H2];
#pragma unroll
      for (int u = 0; u < H2; ++u) w[u] = W[(size_t)(p0 + pp) * N + h0 + u * 64 + hl];
#pragma unroll
      for (int i = 0; i < 16; ++i) {
        float zv = zl[gq * 16 + i][pp];
#pragma unroll
        for (int u = 0; u < H2; ++u) acc[i][u] += zv * w[u];
      }
    }
    __syncthreads();
  }
#pragma unroll
  for (int i = 0; i < 16; ++i)
#pragma unroll
    for (int u = 0; u < H2; ++u)
      partial[((size_t)s * 64 + gq * 16 + i) * N + h0 + u * 64 + hl] = acc[i][u];
}

// ---------------- reduce K-splits + bias ----------------
__global__ __launch_bounds__(256) void k_reduce(const float* __restrict__ partial,
                                                const float* __restrict__ bias,
                                                float* __restrict__ out, int S, int N) {
  int idx = blockIdx.x * 256 + threadIdx.x;
  if (idx >= 64 * N) return;
  int h = idx % N;
  float a = bias[h];
  for (int s = 0; s < S; ++s) a += partial[(size_t)s * 64 * N + idx];
  out[idx] = a;
}

// ---------------- column-wise BN over 64 rows + ReLU ----------------
__global__ __launch_bounds__(64) void k_bn_relu(const float* __restrict__ in,
                                                const float* __restrict__ gamma,
                                                const float* __restrict__ beta,
                                                float* __restrict__ out, int N) {
  int h = blockIdx.x;
  int g = threadIdx.x;
  float v = in[(size_t)g * N + h];
  float s = v, s2 = v * v;
#pragma unroll
  for (int o = 32; o > 0; o >>= 1) {
    s += __shfl_xor(s, o);
    s2 += __shfl_xor(s2, o);
  }
  float m = s * (1.f / 64.f);
  float var = s2 * (1.f / 64.f) - m * m;
  float r = (v - m) * rsqrtf(var + EPSV) * gamma[h] + beta[h];
  out[(size_t)g * N + h] = fmaxf(r, 0.f);
}

// ---------------- final: out = A @ w4 + b4, [64,256]@[256,2] ----------------
__global__ __launch_bounds__(128) void k_final(const float* __restrict__ A,
                                               const float* __restrict__ w4,
                                               const float* __restrict__ b4,
                                               float* __restrict__ out) {
  int t = threadIdx.x;
  if (t >= 128) return;
  int g = t >> 1, c = t & 1;
  float a = b4[c];
  for (int k = 0; k < 256; ++k) a += A[(size_t)g * 256 + k] * w4[k * 2 + c];
  out[g * 2 + c] = a;
}

extern "C" void kernel_launch(void* const* d_in, const int* in_sizes, int n_in,
                              void* d_out, int out_size, void* d_ws, size_t ws_size,
                              hipStream_t stream) {
  const float* x = (const float*)d_in[0];
  const int* edge = (const int*)d_in[1];
  const int* batch = (const int*)d_in[2];
  // d_in[3],[4] lin_src_w/b: dead. d_in[7],[8] att_w/b: dead (softmax over singleton = 1).
  const float* lin_dst_w = (const float*)d_in[5];
  const float* lin_dst_b = (const float*)d_in[6];
  const float* bn_g = (const float*)d_in[9];
  const float* bn_b = (const float*)d_in[10];
  const float* bnh_g = (const float*)d_in[11];
  const float* bnh_b = (const float*)d_in[12];
  const float* w1 = (const float*)d_in[13];
  const float* b1 = (const float*)d_in[14];
  const float* g1 = (const float*)d_in[15];
  const float* be1 = (const float*)d_in[16];
  const float* w2 = (const float*)d_in[17];
  const float* b2 = (const float*)d_in[18];
  const float* g2 = (const float*)d_in[19];
  const float* be2 = (const float*)d_in[20];
  const float* w3 = (const float*)d_in[21];
  const float* b3 = (const float*)d_in[22];
  const float* g3 = (const float*)d_in[23];
  const float* be3 = (const float*)d_in[24];
  const float* w4 = (const float*)d_in[25];
  const float* b4 = (const float*)d_in[26];
  const int* dstp = edge + EE;  // edge_index[1]

  char* ws = (char*)d_ws;
  int* deg = (int*)(ws);                                     // 64 KB
  int* cnt = (int*)(ws + 65536);                             // 256 B
  float* bufA = (float*)(ws + 131072);                       // 16 MiB
  float* bufB = (float*)(ws + 131072 + 16777216);            // 16 MiB
  float* pooled = (float*)(ws + 131072 + 2 * 16777216);      // 192 KB
  char* tail = ws + 131072 + 2 * 16777216 + 196608;
  float* m1 = (float*)(tail);                                // 64x512
  float* m1b = (float*)(tail + 131072);
  float* m2 = (float*)(tail + 262144);                       // 64x256
  float* m2b = (float*)(tail + 262144 + 65536);
  float* m3 = (float*)(tail + 262144 + 131072);
  float* m3b = (float*)(tail + 262144 + 196608);
  float* z = bufA;       // reused after layer-3 pooling (8.55 MB <= 16 MiB)
  float* partial = bufB; // S=128: 128*64*512*4 = 16,777,216 B == bufB exactly

  hipMemsetAsync(ws, 0, 131072, stream);            // deg + cnt
  hipMemsetAsync(pooled, 0, 196608, stream);        // pooled accumulators

  k_deg<<<(EE + 255) / 256, 256, 0, stream>>>(dstp, deg);
  k_cnt<<<(NN + 255) / 256, 256, 0, stream>>>(batch, cnt);

  // ---- 3 conv layers: h = deg * (h @ Wd + bd); pooled[l] += per-graph sums ----
  const float* hin = x;
  float* houts[3] = {bufA, bufB, bufA};
  for (int l = 0; l < LL; ++l) {
    k_gemm_layer<<<dim3(4, 128), 256, 0, stream>>>(hin, lin_dst_w + (size_t)l * FF * FF,
                                                   lin_dst_b + (size_t)l * FF, deg, houts[l]);
    k_pool<<<256, 256, 0, stream>>>(houts[l], batch, pooled, l * FF);
    hin = houts[l];
  }

  // ---- build z = [BN(xt) | BN(pooled/cnt)] ----
  k_xt_bn<<<256, 256, 0, stream>>>(x, bn_g, bn_b, z);
  k_pool_bn<<<3, 256, 0, stream>>>(pooled, cnt, bnh_g, bnh_b, z);

  // ---- MLP ----
  k_w1<<<dim3(8, 128), 256, 0, stream>>>(z, w1, partial);
  k_reduce<<<128, 256, 0, stream>>>(partial, b1, m1, 128, HIDN);
  k_bn_relu<<<HIDN, 64, 0, stream>>>(m1, g1, be1, m1b, HIDN);

  k_skinny<1><<<dim3(4, 4), 256, 0, stream>>>(m1b, w2, partial, HIDN, 256);
  k_reduce<<<64, 256, 0, stream>>>(partial, b2, m2, 4, 256);
  k_bn_relu<<<256, 64, 0, stream>>>(m2, g2, be2, m2b, 256);

  k_skinny<1><<<dim3(4, 2), 256, 0, stream>>>(m2b, w3, partial, 256, 256);
  k_reduce<<<64, 256, 0, stream>>>(partial, b3, m3, 2, 256);
  k_bn_relu<<<256, 64, 0, stream>>>(m3, g3, be3, m3b, 256);

  k_final<<<1, 128, 0, stream>>>(m3b, w4, b4, (float*)d_out);
}

// Round 4
// 349.565 us; speedup vs baseline: 1.4156x; 1.2572x over previous
//
#include <hip/hip_runtime.h>
#include <cstdint>

static constexpr int NN = 16384, FF = 256, GG = 64, EE = 131072, LL = 3;
static constexpr int HIDN = 512, IU = 32640, IN1 = 33408;
#define EPSV 1e-5f

// ---------------- deg histogram (random dst, scattered atomics) + cnt (LDS histogram) ----
__global__ __launch_bounds__(256) void k_hist(const int* __restrict__ dst,
                                              const int* __restrict__ batch,
                                              int* __restrict__ deg, int* __restrict__ cnt) {
  __shared__ int hist[64];
  int bx = blockIdx.x, t = threadIdx.x;
  if (bx < 512) {                      // EE = 512*256 exactly
    int e = bx * 256 + t;
    atomicAdd(&deg[dst[e]], 1);
  } else {                             // 16 blocks x 256 thr x int4 = 16384 nodes
    if (t < 64) hist[t] = 0;
    __syncthreads();
    int4 v = ((const int4*)batch)[(bx - 512) * 256 + t];
    int a[4] = {v.x, v.y, v.z, v.w};
    int cur = a[0], run = 1;
#pragma unroll
    for (int j = 1; j < 4; ++j) {
      if (a[j] == cur) run++;
      else { atomicAdd(&hist[cur], run); cur = a[j]; run = 1; }
    }
    atomicAdd(&hist[cur], run);
    __syncthreads();
    if (t < 64 && hist[t]) atomicAdd(&cnt[t], hist[t]);
  }
}

// ---------------- layer GEMM v2: C = deg * (A @ W + b), 128x64 tile, 8x4/thread ----------------
__global__ __launch_bounds__(256) void k_gemm_layer(const float* __restrict__ A,
                                                    const float* __restrict__ W,
                                                    const float* __restrict__ bias,
                                                    const int* __restrict__ deg,
                                                    float* __restrict__ C) {
  __shared__ float As[16][136];  // A^T tile: As[k][m], m<128
  __shared__ float Bs[16][68];   // Bs[k][n], n<64
  int m0 = blockIdx.y * 128, n0 = blockIdx.x * 64;
  int tid = threadIdx.x;
  int tx = tid & 15, ty = tid >> 4;   // cols tx*4, rows ty*8..+8
  float acc[8][4] = {};
  for (int k0 = 0; k0 < FF; k0 += 16) {
#pragma unroll
    for (int q = 0; q < 2; ++q) {
      int idx = q * 256 + tid;
      int m = idx >> 2, kq = idx & 3;
      float4 v = *(const float4*)(A + (size_t)(m0 + m) * FF + k0 + kq * 4);
      As[kq * 4 + 0][m] = v.x;
      As[kq * 4 + 1][m] = v.y;
      As[kq * 4 + 2][m] = v.z;
      As[kq * 4 + 3][m] = v.w;
    }
    {
      int k = tid >> 4, nq = tid & 15;
      *(float4*)&Bs[k][nq * 4] = *(const float4*)(W + (size_t)(k0 + k) * FF + n0 + nq * 4);
    }
    __syncthreads();
#pragma unroll
    for (int k = 0; k < 16; ++k) {
      float a[8], b[4];
      *(float4*)&a[0] = *(float4*)&As[k][ty * 8];
      *(float4*)&a[4] = *(float4*)&As[k][ty * 8 + 4];
      *(float4*)&b[0] = *(float4*)&Bs[k][tx * 4];
#pragma unroll
      for (int i = 0; i < 8; ++i)
#pragma unroll
        for (int j = 0; j < 4; ++j) acc[i][j] = fmaf(a[i], b[j], acc[i][j]);
    }
    __syncthreads();
  }
  float bb[4];
#pragma unroll
  for (int j = 0; j < 4; ++j) bb[j] = bias[n0 + tx * 4 + j];
#pragma unroll
  for (int i = 0; i < 8; ++i) {
    int row = m0 + ty * 8 + i;
    float df = (float)(deg[row] + 1);  // +1 = self loop
    float4 o;
    o.x = df * (acc[i][0] + bb[0]);
    o.y = df * (acc[i][1] + bb[1]);
    o.z = df * (acc[i][2] + bb[2]);
    o.w = df * (acc[i][3] + bb[3]);
    *(float4*)(C + (size_t)row * FF + n0 + tx * 4) = o;
  }
}

// ---------------- pooling: pooled[g][lofs+f] += sum over rows of graph g ----------------
__global__ __launch_bounds__(256) void k_pool(const float* __restrict__ h,
                                              const int* __restrict__ batch,
                                              float* __restrict__ pooled, int lofs) {
  int n0 = blockIdx.x * 64;
  int f = threadIdx.x;
  float run = 0.f;
  int gprev = batch[n0];
  for (int r = 0; r < 64; ++r) {
    int n = n0 + r;
    int g = batch[n];
    if (g != gprev) {
      atomicAdd(&pooled[(size_t)gprev * (FF * LL) + lofs + f], run);
      run = 0.f;
      gprev = g;
    }
    run += h[(size_t)n * FF + f];
  }
  atomicAdd(&pooled[(size_t)gprev * (FF * LL) + lofs + f], run);
}

// ---------------- front BN: xt (blocks 0..255) + pooled (blocks 256..258) -> z ----------------
__global__ __launch_bounds__(256) void k_bn_front(const float* __restrict__ x,
                                                  const float* __restrict__ bn_g,
                                                  const float* __restrict__ bn_b,
                                                  const float* __restrict__ pooled,
                                                  const int* __restrict__ cnt,
                                                  const float* __restrict__ bnh_g,
                                                  const float* __restrict__ bnh_b,
                                                  float* __restrict__ z) {
  int bx = blockIdx.x;
  if (bx < 256) {
    int i = bx, j = threadIdx.x;
    if (j <= i) return;
    int p = i * 255 - (i * (i - 1)) / 2 + (j - i - 1);
    float vals[64];
    float s = 0.f, s2 = 0.f;
#pragma unroll
    for (int g = 0; g < 64; ++g) {
      float v = x[(size_t)(g * 256 + i) * FF + j];
      vals[g] = v;
      s += v;
      s2 += v * v;
    }
    float m = s * (1.f / 64.f);
    float var = s2 * (1.f / 64.f) - m * m;
    float rs = rsqrtf(var + EPSV) * bn_g[p];
    float bb = bn_b[p];
#pragma unroll
    for (int g = 0; g < 64; ++g) z[(size_t)g * IN1 + p] = (vals[g] - m) * rs + bb;
  } else {
    int q = (bx - 256) * 256 + threadIdx.x;
    if (q >= FF * LL) return;
    float vals[64];
    float s = 0.f, s2 = 0.f;
#pragma unroll
    for (int g = 0; g < 64; ++g) {
      float v = pooled[(size_t)g * (FF * LL) + q] / (float)cnt[g];
      vals[g] = v;
      s += v;
      s2 += v * v;
    }
    float m = s * (1.f / 64.f);
    float var = s2 * (1.f / 64.f) - m * m;
    float rs = rsqrtf(var + EPSV) * bnh_g[q];
    float bb = bnh_b[q];
#pragma unroll
    for (int g = 0; g < 64; ++g) z[(size_t)g * IN1 + IU + q] = (vals[g] - m) * rs + bb;
  }
}

// ---------------- w1 GEMM: partial[s][g][h] for [64,33408]@[33408,512] ----------------
__global__ __launch_bounds__(256) void k_w1(const float* __restrict__ Z,
                                            const float* __restrict__ W,
                                            float* __restrict__ partial) {
  __shared__ float zl[64][132];
  int n0 = blockIdx.x * 64;
  int s = blockIdx.y;
  int tid = threadIdx.x;
  int hq = tid & 15, gq = tid >> 4;
  float acc[4][4] = {};
  for (int c = s; c < 261; c += 128) {  // 33408 = 261*128 exactly
    int p0 = c << 7;
#pragma unroll
    for (int it = 0; it < 8; ++it) {
      int idx = it * 256 + tid;
      int g = idx >> 5, kq = idx & 31;
      *(float4*)&zl[g][kq * 4] = *(const float4*)(Z + (size_t)g * IN1 + p0 + kq * 4);
    }
    __syncthreads();
    const float* wp = W + (size_t)p0 * HIDN + n0 + hq * 4;
    float4 w0 = *(const float4*)(wp);
    float4 w1 = *(const float4*)(wp + HIDN);
#pragma unroll 4
    for (int kk = 0; kk < 128; ++kk) {
      int kn = kk + 2 < 128 ? kk + 2 : 127;
      float4 w2 = *(const float4*)(wp + (size_t)kn * HIDN);
      float zv[4];
#pragma unroll
      for (int i = 0; i < 4; ++i) zv[i] = zl[gq * 4 + i][kk];
#pragma unroll
      for (int i = 0; i < 4; ++i) {
        acc[i][0] = fmaf(zv[i], w0.x, acc[i][0]);
        acc[i][1] = fmaf(zv[i], w0.y, acc[i][1]);
        acc[i][2] = fmaf(zv[i], w0.z, acc[i][2]);
        acc[i][3] = fmaf(zv[i], w0.w, acc[i][3]);
      }
      w0 = w1;
      w1 = w2;
    }
    __syncthreads();
  }
#pragma unroll
  for (int i = 0; i < 4; ++i) {
    int g = gq * 4 + i;
    *(float4*)(partial + ((size_t)s * 64 + g) * HIDN + n0 + hq * 4) = *(float4*)&acc[i][0];
  }
}

// ---------------- reduce K-splits + bias ----------------
__global__ __launch_bounds__(256) void k_reduce(const float* __restrict__ partial,
                                                const float* __restrict__ bias,
                                                float* __restrict__ out, int S, int N) {
  int idx = blockIdx.x * 256 + threadIdx.x;
  if (idx >= 64 * N) return;
  int h = idx % N;
  float a = bias[h];
  for (int s = 0; s < S; ++s) a += partial[(size_t)s * 64 * N + idx];
  out[idx] = a;
}

// ---------------- column-wise BN over 64 rows + ReLU ----------------
__global__ __launch_bounds__(64) void k_bn_relu(const float* __restrict__ in,
                                                const float* __restrict__ gamma,
                                                const float* __restrict__ beta,
                                                float* __restrict__ out, int N) {
  int h = blockIdx.x;
  int g = threadIdx.x;
  float v = in[(size_t)g * N + h];
  float s = v, s2 = v * v;
#pragma unroll
  for (int o = 32; o > 0; o >>= 1) {
    s += __shfl_xor(s, o);
    s2 += __shfl_xor(s2, o);
  }
  float m = s * (1.f / 64.f);
  float var = s2 * (1.f / 64.f) - m * m;
  float r = (v - m) * rsqrtf(var + EPSV) * gamma[h] + beta[h];
  out[(size_t)g * N + h] = fmaxf(r, 0.f);
}

// ---------------- fused small MLP layer: out = relu(BN(Z@W + b)), M=64 ----------------
// grid N/64 blocks x 512 threads; block owns 64 full output columns (so BN stats are local)
__global__ __launch_bounds__(512) void k_mlp_small(const float* __restrict__ Z,
                                                   const float* __restrict__ W,
                                                   const float* __restrict__ bias,
                                                   const float* __restrict__ gamma,
                                                   const float* __restrict__ beta,
                                                   float* __restrict__ out, int K, int N) {
  __shared__ float zl[64][132];
  __shared__ float sb1[8][72], sb2[8][72];
  int t = threadIdx.x;
  int hl = t & 63, gq = t >> 6;        // gq in 0..7, 8 g-rows per thread
  int h0 = blockIdx.x * 64;
  float acc[8] = {};
  for (int c = 0; c < K; c += 128) {
#pragma unroll
    for (int it = 0; it < 4; ++it) {
      int idx = it * 512 + t;          // < 2048 = 64*128/4
      int g = idx >> 5, kq = idx & 31;
      *(float4*)&zl[g][kq * 4] = *(const float4*)(Z + (size_t)g * K + c + kq * 4);
    }
    __syncthreads();
    for (int kk = 0; kk < 128; ++kk) {
      float w = W[(size_t)(c + kk) * N + h0 + hl];
#pragma unroll
      for (int i = 0; i < 8; ++i) acc[i] = fmaf(zl[gq * 8 + i][kk], w, acc[i]);
    }
    __syncthreads();
  }
  float bb = bias[h0 + hl];
  float s1 = 0.f, s2 = 0.f;
#pragma unroll
  for (int i = 0; i < 8; ++i) {
    acc[i] += bb;
    s1 += acc[i];
    s2 += acc[i] * acc[i];
  }
  sb1[gq][hl] = s1;
  sb2[gq][hl] = s2;
  __syncthreads();
  float S1 = 0.f, S2 = 0.f;
#pragma unroll
  for (int q = 0; q < 8; ++q) { S1 += sb1[q][hl]; S2 += sb2[q][hl]; }
  float m = S1 * (1.f / 64.f);
  float var = S2 * (1.f / 64.f) - m * m;
  float rs = rsqrtf(var + EPSV) * gamma[h0 + hl];
  float be = beta[h0 + hl];
#pragma unroll
  for (int i = 0; i < 8; ++i)
    out[(size_t)(gq * 8 + i) * N + h0 + hl] = fmaxf((acc[i] - m) * rs + be, 0.f);
}

// ---------------- final: out = A @ w4 + b4, [64,256]@[256,2], wave-parallel ----------------
__global__ __launch_bounds__(256) void k_final(const float* __restrict__ A,
                                               const float* __restrict__ w4,
                                               const float* __restrict__ b4,
                                               float* __restrict__ out) {
  __shared__ float w4l[512];
  int t = threadIdx.x;
  w4l[t] = w4[t];
  w4l[256 + t] = w4[256 + t];
  __syncthreads();
  int w = t >> 6, l = t & 63;
  for (int g = w * 16; g < w * 16 + 16; ++g) {
    float4 av = *(const float4*)(A + (size_t)g * 256 + l * 4);
    float c0 = av.x * w4l[(l * 4 + 0) * 2] + av.y * w4l[(l * 4 + 1) * 2] +
               av.z * w4l[(l * 4 + 2) * 2] + av.w * w4l[(l * 4 + 3) * 2];
    float c1 = av.x * w4l[(l * 4 + 0) * 2 + 1] + av.y * w4l[(l * 4 + 1) * 2 + 1] +
               av.z * w4l[(l * 4 + 2) * 2 + 1] + av.w * w4l[(l * 4 + 3) * 2 + 1];
#pragma unroll
    for (int o = 32; o > 0; o >>= 1) {
      c0 += __shfl_xor(c0, o);
      c1 += __shfl_xor(c1, o);
    }
    if (l == 0) {
      out[g * 2 + 0] = c0 + b4[0];
      out[g * 2 + 1] = c1 + b4[1];
    }
  }
}

extern "C" void kernel_launch(void* const* d_in, const int* in_sizes, int n_in,
                              void* d_out, int out_size, void* d_ws, size_t ws_size,
                              hipStream_t stream) {
  const float* x = (const float*)d_in[0];
  const int* edge = (const int*)d_in[1];
  const int* batch = (const int*)d_in[2];
  // d_in[3],[4] lin_src_w/b: dead. d_in[7],[8] att_w/b: dead (softmax over singleton = 1).
  const float* lin_dst_w = (const float*)d_in[5];
  const float* lin_dst_b = (const float*)d_in[6];
  const float* bn_g = (const float*)d_in[9];
  const float* bn_b = (const float*)d_in[10];
  const float* bnh_g = (const float*)d_in[11];
  const float* bnh_b = (const float*)d_in[12];
  const float* w1 = (const float*)d_in[13];
  const float* b1 = (const float*)d_in[14];
  const float* g1 = (const float*)d_in[15];
  const float* be1 = (const float*)d_in[16];
  const float* w2 = (const float*)d_in[17];
  const float* b2 = (const float*)d_in[18];
  const float* g2 = (const float*)d_in[19];
  const float* be2 = (const float*)d_in[20];
  const float* w3 = (const float*)d_in[21];
  const float* b3 = (const float*)d_in[22];
  const float* g3 = (const float*)d_in[23];
  const float* be3 = (const float*)d_in[24];
  const float* w4 = (const float*)d_in[25];
  const float* b4 = (const float*)d_in[26];
  const int* dstp = edge + EE;  // edge_index[1]

  char* ws = (char*)d_ws;
  int* deg = (int*)(ws);                                     // 64 KB
  int* cnt = (int*)(ws + 65536);                             // 256 B
  float* bufA = (float*)(ws + 131072);                       // 16 MiB
  float* bufB = (float*)(ws + 131072 + 16777216);            // 16 MiB
  float* pooled = (float*)(ws + 131072 + 2 * 16777216);      // 192 KB
  char* tail = ws + 131072 + 2 * 16777216 + 196608;
  float* m1 = (float*)(tail);                                // 64x512
  float* m1b = (float*)(tail + 131072);
  float* m2b = (float*)(tail + 262144);                      // 64x256
  float* m3b = (float*)(tail + 262144 + 65536);
  float* z = bufA;       // reused after layer-3 pooling (8.55 MB <= 16 MiB)
  float* partial = bufB; // S=128: 128*64*512*4 = 16,777,216 B == bufB exactly

  hipMemsetAsync(ws, 0, 131072, stream);            // deg + cnt
  hipMemsetAsync(pooled, 0, 196608, stream);        // pooled accumulators

  k_hist<<<528, 256, 0, stream>>>(dstp, batch, deg, cnt);

  // ---- 3 conv layers: h = deg * (h @ Wd + bd); pooled[l] += per-graph sums ----
  const float* hin = x;
  float* houts[3] = {bufA, bufB, bufA};
  for (int l = 0; l < LL; ++l) {
    k_gemm_layer<<<dim3(4, 128), 256, 0, stream>>>(hin, lin_dst_w + (size_t)l * FF * FF,
                                                   lin_dst_b + (size_t)l * FF, deg, houts[l]);
    k_pool<<<256, 256, 0, stream>>>(houts[l], batch, pooled, l * FF);
    hin = houts[l];
  }

  // ---- build z = [BN(xt) | BN(pooled/cnt)] ----
  k_bn_front<<<259, 256, 0, stream>>>(x, bn_g, bn_b, pooled, cnt, bnh_g, bnh_b, z);

  // ---- MLP ----
  k_w1<<<dim3(8, 128), 256, 0, stream>>>(z, w1, partial);
  k_reduce<<<128, 256, 0, stream>>>(partial, b1, m1, 128, HIDN);
  k_bn_relu<<<HIDN, 64, 0, stream>>>(m1, g1, be1, m1b, HIDN);

  k_mlp_small<<<4, 512, 0, stream>>>(m1b, w2, b2, g2, be2, m2b, HIDN, 256);
  k_mlp_small<<<4, 512, 0, stream>>>(m2b, w3, b3, g3, be3, m3b, 256, 256);

  k_final<<<1, 256, 0, stream>>>(m3b, w4, b4, (float*)d_out);
}